// Round 21
// baseline (94.998 us; speedup 1.0000x reference)
//
#include <hip/hip_runtime.h>

// Problem constants
#define B_   64
#define M_   256
#define D_   256
#define A_   18
#define E_   4
#define S_   64
#define ES_  256          // E_*S_ == M_
#define H_   512
#define K2_  (A_*D_)      // 4608

typedef _Float16 f16;
typedef _Float16 f16x4 __attribute__((ext_vector_type(4)));
typedef _Float16 f16x8 __attribute__((ext_vector_type(8)));
typedef float    f32x4 __attribute__((ext_vector_type(4)));

static __device__ __forceinline__ f16x8 cat8(f16x4 a, f16x4 b) {
  return __builtin_shufflevector(a, b, 0, 1, 2, 3, 4, 5, 6, 7);
}
static __device__ __forceinline__ f16x8 pack8(float4 u0, float4 u1) {
  f16x8 a;
  a[0] = (f16)u0.x; a[1] = (f16)u0.y; a[2] = (f16)u0.z; a[3] = (f16)u0.w;
  a[4] = (f16)u1.x; a[5] = (f16)u1.y; a[6] = (f16)u1.z; a[7] = (f16)u1.w;
  return a;
}

// async global->LDS, 16B per lane; lds dest is wave-uniform base (+lane*16 HW)
typedef const __attribute__((address_space(1))) unsigned int guint;
typedef __attribute__((address_space(3))) unsigned int luint;
static __device__ __forceinline__ void gload16(const f16* g, f16* l) {
  __builtin_amdgcn_global_load_lds((guint*)g, (luint*)l, 16, 0, 0);
}
#define VMCNT(n)  asm volatile("s_waitcnt vmcnt(" #n ")" ::: "memory")
#define LGKMCNT0  asm volatile("s_waitcnt lgkmcnt(0)" ::: "memory")
#define SBAR()    __builtin_amdgcn_s_barrier()
#define SCHED0()  __builtin_amdgcn_sched_barrier(0)
#define MFMA16(a, b, c) __builtin_amdgcn_mfma_f32_16x16x32_f16(a, b, c, 0, 0, 0)

// ===========================================================================
// k_preplog: ONE launch = all conversions + logits/exp/partial-sums.
// R21: transpose-convert restructured to 256-row x 64-col tiles:
//  - 16 independent float4 loads/thread (deep ILP, no intermediate barrier)
//  - destination rows written as 512 CONTIGUOUS bytes (f16x8 stores)
//  - 864 transpose blocks instead of 3456
// Block ranges:
//   [0,256)     obs  [b][256][256] -> obsT16 [b][256][256]   (64 b x 4 ct)
//   [256,288)   w1   [e][256][512] -> w1T    [e][512][256]   (4 e x 8 ct)
//   [288,864)   w2   [e][512][4608]-> w2T    [e][4608][512]  (4e x 2rt x 72ct)
//   [864]       action rank-sort -> order
//   [865,1889)  logits: exp16/expT16/rowpart/colpart (stages phi^T itself)
// ===========================================================================
__global__ __launch_bounds__(256) void k_preplog(
    const float* __restrict__ obs, const float* __restrict__ phi,
    const float* __restrict__ w1, const float* __restrict__ w2,
    const int* __restrict__ action,
    f16* __restrict__ obsT16, f16* __restrict__ w1T, f16* __restrict__ w2T,
    int* __restrict__ order,
    f16* __restrict__ exp16, f16* __restrict__ expT16,
    float* __restrict__ rowpart, float* __restrict__ colpart)
{
  __shared__ f16 sh[64 * 268];                      // 34.3 KB
  const int bx = blockIdx.x;
  const int t  = threadIdx.x;

  if (bx < 864) {
    // ---------------- transpose+convert 256x64 tile ----------------
    // T[col 64][row 268-stride]: stride 268 -> f16x4 reads 2-way (free)
    const float* src; f16* dst; int C, R; long r0; int c0;
    if (bx < 256) {
      const int z = bx >> 2, x = bx & 3;
      src = obs + (long)z * (M_ * D_); dst = obsT16 + (long)z * (M_ * D_);
      C = D_; R = M_; r0 = 0; c0 = x * 64;
    } else if (bx < 288) {
      const int idx = bx - 256, e = idx >> 3, x = idx & 7;
      src = w1 + (long)e * (D_ * H_); dst = w1T + (long)e * (H_ * D_);
      C = H_; R = D_; r0 = 0; c0 = x * 64;
    } else {
      const int idx = bx - 288, e = idx / 144, rem = idx % 144;
      const int rt = rem / 72, x = rem % 72;
      src = w2 + (long)e * ((long)H_ * K2_);
      dst = w2T + (long)e * ((long)K2_ * H_);
      C = K2_; R = H_; r0 = (long)rt * 256; c0 = x * 64;
    }
    {
      const int q = t & 15, rr = t >> 4;     // q: col-float4, rr: row-in-pass
#pragma unroll
      for (int p = 0; p < 16; ++p) {
        const int row = p * 16 + rr;
        const float4 v = *reinterpret_cast<const float4*>(
            &src[(r0 + row) * C + c0 + q * 4]);
        sh[(q * 4 + 0) * 268 + row] = (f16)v.x;
        sh[(q * 4 + 1) * 268 + row] = (f16)v.y;
        sh[(q * 4 + 2) * 268 + row] = (f16)v.z;
        sh[(q * 4 + 3) * 268 + row] = (f16)v.w;
      }
    }
    __syncthreads();
    {
      const int oc = t >> 2, ch = t & 3;     // oc: dst row (src col), ch: 64-elem chunk
      f16* drow = dst + (long)(c0 + oc) * R + r0 + ch * 64;
      const f16* srow = &sh[oc * 268 + ch * 64];
#pragma unroll
      for (int j = 0; j < 8; ++j) {
        const f16x4 a = *reinterpret_cast<const f16x4*>(srow + j * 8);
        const f16x4 b = *reinterpret_cast<const f16x4*>(srow + j * 8 + 4);
        *reinterpret_cast<f16x8*>(drow + j * 8) = cat8(a, b);
      }
    }
    return;
  }

  if (bx == 864) {
    // ---------------- action rank-sort ----------------
    if (t < B_) {
      const int a = action[t];
      int rank = 0;
#pragma unroll 8
      for (int i = 0; i < B_; ++i) {
        const int ai = action[i];
        rank += (ai < a) || (ai == a && i < t);
      }
      order[rank] = t;
    }
    return;
  }

  // ---------------- logits + exp + partial sums ----------------
  f16 (*Bs)[264] = reinterpret_cast<f16(*)[264]>(&sh[0]);
  f16 (*T)[68]   = reinterpret_cast<f16(*)[68]>(&sh[0]);
  const int lb  = bx - 865;
  const int es0 = (lb & 3) * 64, m0g = ((lb >> 2) & 3) * 64;
  const int bz  = lb >> 4;
  const long bo = (long)bz * (M_ * D_);
  const long bb = (long)bz * (M_ * ES_);

  {
    const int el = t & 63, wg = t >> 6;
#pragma unroll
    for (int dp = 0; dp < D_; dp += 32) {
      f16x8 hv;
#pragma unroll
      for (int j = 0; j < 8; ++j)
        hv[j] = (f16)phi[(long)(dp + wg * 8 + j) * ES_ + es0 + el];
      *reinterpret_cast<f16x8*>(&Bs[el][dp + wg * 8]) = hv;
    }
  }
  __syncthreads();

  const int w = t >> 6, lane = t & 63;
  const int wr = w >> 1, wc = w & 1;
  const int lr = lane & 15, lk = (lane >> 4) * 8;
  const int orow = (lane >> 4) * 4;

  f32x4 acc[2][2] = {};
  const float* Ap = obs + bo + (long)(m0g + wr * 32 + lr) * D_ + lk;
#pragma unroll
  for (int k0 = 0; k0 < D_; k0 += 32) {
    const float4 u00 = *reinterpret_cast<const float4*>(Ap + k0);
    const float4 u01 = *reinterpret_cast<const float4*>(Ap + k0 + 4);
    const float4 u10 = *reinterpret_cast<const float4*>(Ap + 16 * D_ + k0);
    const float4 u11 = *reinterpret_cast<const float4*>(Ap + 16 * D_ + k0 + 4);
    const f16x8 a0 = pack8(u00, u01);
    const f16x8 a1 = pack8(u10, u11);
    const f16x8 b0 = *reinterpret_cast<const f16x8*>(&Bs[wc * 32 + lr][k0 + lk]);
    const f16x8 b1 = *reinterpret_cast<const f16x8*>(&Bs[wc * 32 + 16 + lr][k0 + lk]);
    acc[0][0] = MFMA16(a0, b0, acc[0][0]);
    acc[0][1] = MFMA16(a0, b1, acc[0][1]);
    acc[1][0] = MFMA16(a1, b0, acc[1][0]);
    acc[1][1] = MFMA16(a1, b1, acc[1][1]);
  }
  __syncthreads();   // Bs dead; reuse as T

#pragma unroll
  for (int fi = 0; fi < 2; ++fi)
#pragma unroll
    for (int fj = 0; fj < 2; ++fj) {
      const int gm = wr * 32 + fi * 16 + orow;
      const int gn = wc * 32 + fj * 16 + lr;
#pragma unroll
      for (int r = 0; r < 4; ++r)
        T[gm + r][gn] = (f16)__expf(acc[fi][fj][r]);
    }
  __syncthreads();

  {
    const int row = t >> 2, q = t & 3;
    f16x4 p0 = *reinterpret_cast<const f16x4*>(&T[row][q * 16 + 0]);
    f16x4 p1 = *reinterpret_cast<const f16x4*>(&T[row][q * 16 + 4]);
    f16x4 p2 = *reinterpret_cast<const f16x4*>(&T[row][q * 16 + 8]);
    f16x4 p3 = *reinterpret_cast<const f16x4*>(&T[row][q * 16 + 12]);
    f16* dst = exp16 + bb + (long)(m0g + row) * ES_ + es0 + q * 16;
    *reinterpret_cast<f16x8*>(dst)     = cat8(p0, p1);
    *reinterpret_cast<f16x8*>(dst + 8) = cat8(p2, p3);
  }
  {
    const int er = t >> 2, q = t & 3;
    f16x4 g[4];
#pragma unroll
    for (int j = 0; j < 4; ++j)
#pragma unroll
      for (int i = 0; i < 4; ++i)
        g[j][i] = T[q * 16 + j * 4 + i][er];
    f16* dst = expT16 + bb + (long)(es0 + er) * M_ + m0g + q * 16;
    *reinterpret_cast<f16x8*>(dst)     = cat8(g[0], g[1]);
    *reinterpret_cast<f16x8*>(dst + 8) = cat8(g[2], g[3]);
  }
  if (t < 64) {
    float s = 0.f;
#pragma unroll
    for (int i = 0; i < 16; ++i) {
      const f16x4 v = *reinterpret_cast<const f16x4*>(&T[t][i * 4]);
      s += (float)v[0] + (float)v[1] + (float)v[2] + (float)v[3];
    }
    rowpart[((long)bz * 256 + m0g + t) * 4 + (lb & 3)] = s;
  } else if (t < 128) {
    const int es = t - 64;
    float s = 0.f;
#pragma unroll
    for (int i = 0; i < 64; ++i) s += (float)T[i][es];
    colpart[((long)bz * 256 + es0 + es) * 4 + ((lb >> 2) & 3)] = s;
  }
}

// ===========================================================================
// k_hy8: fused slots->h->y, pipelined staging via raw s_barrier + counted
// vmcnt (unchanged from R20, 89.7 µs baseline).
// ===========================================================================
__global__ __launch_bounds__(512, 4) void k_hy8(
    const f16* __restrict__ expT16, const f16* __restrict__ obsT16,
    const float* __restrict__ colpart,
    const f16* __restrict__ w1T, const float* __restrict__ b1,
    const f16* __restrict__ w2T, const float* __restrict__ b2,
    const int* __restrict__ action, const int* __restrict__ order,
    f16* __restrict__ yT16)
{
  __shared__ f16 lds[40960];        // 80 KB exactly
  f16* stg = lds;                   // 2 x 8192
  f16* ssO = lds + 16384;           // 8192
  f16* hsO = lds + 24576;           // 16384

  const int bx = blockIdx.x;
  const int L  = (bx & 7) * 64 + (bx >> 3);   // XCD-chunk swizzle (bijective)
  const int sb = L >> 3, e = (L >> 1) & 3, half = L & 1;   // b-major decode
  const int b = order[sb];
  const int s0 = half * 32;
  int a = action[b];
  a = (a < 0) ? 0 : (a >= A_ ? A_ - 1 : a);

  const int t = threadIdx.x, w = t >> 6, lane = t & 63;
  const int lr = lane & 15, lk = (lane >> 4) * 8;
  const int seg = lane >> 4;
  const int orow = (lane >> 4) * 4;
  const int xorA = (lr & 7) << 3;

  const f16* srcB0 = obsT16 + (long)b * (D_ * M_);
  const f16* srcB1 = w1T + (long)e * (H_ * D_);
  const f16* srcB2 = w2T + (long)e * ((long)K2_ * H_) + (long)a * D_ * H_;
  const f16* ApG0  = expT16 + (long)b * (ES_ * M_)
                   + (long)(e * S_ + s0 + lr) * M_ + lk;

  // ======== GEMM0 (serial staging): ss = (1/colsum)*expT@obsT^T ============
  f32x4 acc00 = {}, acc01 = {}, acc10 = {}, acc11 = {};
#pragma unroll 1
  for (int kt = 0; kt < 8; ++kt) {
    __syncthreads();
#pragma unroll
    for (int p = 0; p < 2; ++p) {
      const int j = (w * 2 + p) * 64 + lane;
      const int row = j >> 2, sg = (j & 3) ^ (row & 3);
      gload16(srcB0 + (long)row * M_ + kt * 32 + sg * 8, stg + (w * 2 + p) * 512);
    }
    __syncthreads();
    const f16x8 a0 = *reinterpret_cast<const f16x8*>(ApG0 + kt * 32);
    const f16x8 a1 = *reinterpret_cast<const f16x8*>(ApG0 + 16 * M_ + kt * 32);
    const int r0 = w * 32 + lr, r1 = w * 32 + 16 + lr;
    const f16x8 b0 = *reinterpret_cast<const f16x8*>(&stg[r0 * 32 + ((seg ^ (r0 & 3)) * 8)]);
    const f16x8 b1 = *reinterpret_cast<const f16x8*>(&stg[r1 * 32 + ((seg ^ (r1 & 3)) * 8)]);
    acc00 = MFMA16(a0, b0, acc00); acc01 = MFMA16(a0, b1, acc01);
    acc10 = MFMA16(a1, b0, acc10); acc11 = MFMA16(a1, b1, acc11);
  }
  __syncthreads();

  // G1 prologue stage 0 (into stg)
#pragma unroll
  for (int p = 0; p < 4; ++p) {
    const int j = (w * 4 + p) * 64 + lane;
    const int row = j >> 2, sg = (j & 3) ^ (row & 3);
    gload16(srcB1 + (long)row * D_ + 0 * 32 + sg * 8, stg + (w * 4 + p) * 512);
  }
  // G0 epilogue -> ssO (XOR-swizzled)
  {
    f32x4 accs[2][2] = {{acc00, acc01}, {acc10, acc11}};
    const int n0 = w * 32;
#pragma unroll
    for (int fi = 0; fi < 2; ++fi) {
      float inv[4];
#pragma unroll
      for (int r = 0; r < 4; ++r) {
        const int ges = e * S_ + s0 + fi * 16 + orow + r;
        const float4 cp = *reinterpret_cast<const float4*>(
            &colpart[((long)b * 256 + ges) * 4]);
        inv[r] = 1.0f / (cp.x + cp.y + cp.z + cp.w);
      }
#pragma unroll
      for (int fj = 0; fj < 2; ++fj) {
        const int gn = n0 + fj * 16 + lr;
#pragma unroll
        for (int r = 0; r < 4; ++r) {
          const int row = fi * 16 + orow + r;
          ssO[row * 256 + (gn ^ ((row & 7) << 3))] = (f16)(accs[fi][fj][r] * inv[r]);
        }
      }
    }
  }
  // G1 prologue stage 1 (into hsO region)
#pragma unroll
  for (int p = 0; p < 4; ++p) {
    const int j = (w * 4 + p) * 64 + lane;
    const int row = j >> 2, sg = (j & 3) ^ (row & 3);
    gload16(srcB1 + (long)row * D_ + 1 * 32 + sg * 8, hsO + (w * 4 + p) * 512);
  }
  LGKMCNT0; SBAR(); SCHED0();

  // ======== GEMM1 (pipelined): hs = relu(ss @ w1T^T + b1) ==================
  f32x4 g1acc[2][4] = {};
#pragma unroll 1
  for (int kt = 0; kt < 7; ++kt) {
    VMCNT(4); SBAR(); SCHED0();
    f16* buf = (kt & 1) ? hsO : stg;
    {
      const f16x8 af0 = *reinterpret_cast<const f16x8*>(
          &ssO[lr * 256 + ((kt * 32 + lk) ^ xorA)]);
      const f16x8 af1 = *reinterpret_cast<const f16x8*>(
          &ssO[(16 + lr) * 256 + ((kt * 32 + lk) ^ xorA)]);
#pragma unroll
      for (int fj = 0; fj < 4; ++fj) {
        const int rB = w * 64 + fj * 16 + lr;
        const f16x8 bf = *reinterpret_cast<const f16x8*>(
            &buf[rB * 32 + ((seg ^ (rB & 3)) * 8)]);
        g1acc[0][fj] = MFMA16(af0, bf, g1acc[0][fj]);
        g1acc[1][fj] = MFMA16(af1, bf, g1acc[1][fj]);
      }
    }
    SBAR();
    if (kt < 6) {
#pragma unroll
      for (int p = 0; p < 4; ++p) {
        const int j = (w * 4 + p) * 64 + lane;
        const int row = j >> 2, sg = (j & 3) ^ (row & 3);
        gload16(srcB1 + (long)row * D_ + (kt + 2) * 32 + sg * 8, buf + (w * 4 + p) * 512);
      }
    }
  }
  VMCNT(0); SBAR(); SCHED0();
  {
    const f16x8 af0 = *reinterpret_cast<const f16x8*>(
        &ssO[lr * 256 + ((7 * 32 + lk) ^ xorA)]);
    const f16x8 af1 = *reinterpret_cast<const f16x8*>(
        &ssO[(16 + lr) * 256 + ((7 * 32 + lk) ^ xorA)]);
#pragma unroll
    for (int fj = 0; fj < 4; ++fj) {
      const int rB = w * 64 + fj * 16 + lr;
      const f16x8 bf = *reinterpret_cast<const f16x8*>(
          &hsO[rB * 32 + ((seg ^ (rB & 3)) * 8)]);
      g1acc[0][fj] = MFMA16(af0, bf, g1acc[0][fj]);
      g1acc[1][fj] = MFMA16(af1, bf, g1acc[1][fj]);
    }
  }
  SBAR();

  // G2 prologue stages 0,1 (into stg halves)
#pragma unroll
  for (int p = 0; p < 2; ++p) {
    const int j = (w * 2 + p) * 64 + lane;
    const int row = j >> 2, sg = (j & 3) ^ (row & 3);
    gload16(srcB2 + (long)row * H_ + 0 * 32 + sg * 8, stg + (w * 2 + p) * 512);
  }
#pragma unroll
  for (int p = 0; p < 2; ++p) {
    const int j = (w * 2 + p) * 64 + lane;
    const int row = j >> 2, sg = (j & 3) ^ (row & 3);
    gload16(srcB2 + (long)row * H_ + 1 * 32 + sg * 8, stg + 8192 + (w * 2 + p) * 512);
  }
  // G1 epilogue -> hsO (XOR-swizzled)
  {
    const int n1 = w * 64;
#pragma unroll
    for (int fi = 0; fi < 2; ++fi)
#pragma unroll
      for (int fj = 0; fj < 4; ++fj) {
        const int gn = n1 + fj * 16 + lr;
        const float bv = b1[e * H_ + gn];
#pragma unroll
        for (int r = 0; r < 4; ++r) {
          const int row = fi * 16 + orow + r;
          hsO[row * 512 + (gn ^ ((row & 7) << 3))] =
              (f16)fmaxf(g1acc[fi][fj][r] + bv, 0.f);
        }
      }
  }
  LGKMCNT0; SBAR(); SCHED0();

  // ======== GEMM2 (pipelined): y = hs @ w2T[a-slice]^T + b2 ================
  f32x4 acc2[2][2] = {};
#pragma unroll 1
  for (int kt = 0; kt < 15; ++kt) {
    VMCNT(2); SBAR(); SCHED0();
    f16* buf = stg + (kt & 1) * 8192;
    {
      const f16x8 af0 = *reinterpret_cast<const f16x8*>(
          &hsO[lr * 512 + ((kt * 32 + lk) ^ xorA)]);
      const f16x8 af1 = *reinterpret_cast<const f16x8*>(
          &hsO[(16 + lr) * 512 + ((kt * 32 + lk) ^ xorA)]);
#pragma unroll
      for (int fj = 0; fj < 2; ++fj) {
        const int rB = w * 32 + fj * 16 + lr;
        const f16x8 bf = *reinterpret_cast<const f16x8*>(
            &buf[rB * 32 + ((seg ^ (rB & 3)) * 8)]);
        acc2[0][fj] = MFMA16(af0, bf, acc2[0][fj]);
        acc2[1][fj] = MFMA16(af1, bf, acc2[1][fj]);
      }
    }
    SBAR();
    if (kt < 14) {
#pragma unroll
      for (int p = 0; p < 2; ++p) {
        const int j = (w * 2 + p) * 64 + lane;
        const int row = j >> 2, sg = (j & 3) ^ (row & 3);
        gload16(srcB2 + (long)row * H_ + (kt + 2) * 32 + sg * 8, buf + (w * 2 + p) * 512);
      }
    }
  }
  VMCNT(0); SBAR(); SCHED0();
  {
    const f16x8 af0 = *reinterpret_cast<const f16x8*>(
        &hsO[lr * 512 + ((15 * 32 + lk) ^ xorA)]);
    const f16x8 af1 = *reinterpret_cast<const f16x8*>(
        &hsO[(16 + lr) * 512 + ((15 * 32 + lk) ^ xorA)]);
#pragma unroll
    for (int fj = 0; fj < 2; ++fj) {
      const int rB = w * 32 + fj * 16 + lr;
      const f16x8 bf = *reinterpret_cast<const f16x8*>(
          &stg[8192 + rB * 32 + ((seg ^ (rB & 3)) * 8)]);
      acc2[0][fj] = MFMA16(af0, bf, acc2[0][fj]);
      acc2[1][fj] = MFMA16(af1, bf, acc2[1][fj]);
    }
  }
  // yT16 epilogue
  {
    const int n0_2 = w * 32;
#pragma unroll
    for (int fi = 0; fi < 2; ++fi)
#pragma unroll
      for (int fj = 0; fj < 2; ++fj) {
        const int gm = fi * 16 + orow;
        const int gn = n0_2 + fj * 16 + lr;
        const float bv = b2[e * K2_ + a * D_ + gn];
        f16x4 h4;
#pragma unroll
        for (int r = 0; r < 4; ++r) h4[r] = (f16)(acc2[fi][fj][r] + bv);
        *reinterpret_cast<f16x4*>(
            &yT16[(long)b * (D_ * ES_) + (long)gn * ES_ + e * S_ + s0 + gm]) = h4;
      }
  }
}

// ===========================================================================
// k_out_s: out[b][m][d] (fp32) = (1/rowsum[m]) * exp16[b] @ yT16[b]^T
// ===========================================================================
__global__ __launch_bounds__(256) void k_out_s(
    const f16* __restrict__ exp16, const f16* __restrict__ yT16,
    const float* __restrict__ rowpart, float* __restrict__ out)
{
  const int t = threadIdx.x;
  const int w = t >> 6, lane = t & 63;
  const int wr = w >> 1, wc = w & 1;
  const int m0 = blockIdx.y * 64 + wr * 32;
  const int n0 = blockIdx.x * 64 + wc * 32;
  const int lr = lane & 15, lk = (lane >> 4) * 8;
  const long b = blockIdx.z;

  f32x4 acc[2][2] = {};
  const f16* Ap = exp16 + b * (M_ * ES_) + (long)(m0 + lr) * ES_ + lk;
  const f16* Bp = yT16 + b * (D_ * ES_) + (long)(n0 + lr) * ES_ + lk;
#pragma unroll
  for (int k0 = 0; k0 < ES_; k0 += 32) {
    const f16x8 a0 = *reinterpret_cast<const f16x8*>(Ap + k0);
    const f16x8 a1 = *reinterpret_cast<const f16x8*>(Ap + 16 * ES_ + k0);
    const f16x8 b0 = *reinterpret_cast<const f16x8*>(Bp + k0);
    const f16x8 b1 = *reinterpret_cast<const f16x8*>(Bp + 16 * ES_ + k0);
    acc[0][0] = MFMA16(a0, b0, acc[0][0]);
    acc[0][1] = MFMA16(a0, b1, acc[0][1]);
    acc[1][0] = MFMA16(a1, b0, acc[1][0]);
    acc[1][1] = MFMA16(a1, b1, acc[1][1]);
  }

  const int orow = (lane >> 4) * 4;
  float* C = out + b * (M_ * D_);
#pragma unroll
  for (int fi = 0; fi < 2; ++fi) {
    float inv[4];
#pragma unroll
    for (int r = 0; r < 4; ++r) {
      const int gm = m0 + fi * 16 + orow + r;
      const float4 rp = *reinterpret_cast<const float4*>(&rowpart[((long)b * 256 + gm) * 4]);
      inv[r] = 1.0f / (rp.x + rp.y + rp.z + rp.w);
    }
#pragma unroll
    for (int fj = 0; fj < 2; ++fj) {
      const int gm = m0 + fi * 16 + orow;
      const int gn = n0 + fj * 16 + lr;
#pragma unroll
      for (int r = 0; r < 4; ++r)
        C[(long)(gm + r) * D_ + gn] = acc[fi][fj][r] * inv[r];
    }
  }
}

// ===========================================================================
extern "C" void kernel_launch(void* const* d_in, const int* in_sizes, int n_in,
                              void* d_out, int out_size, void* d_ws, size_t ws_size,
                              hipStream_t stream)
{
  const float* obs    = (const float*)d_in[0];
  const int*   action = (const int*)d_in[1];
  const float* phi    = (const float*)d_in[2];
  const float* w1     = (const float*)d_in[3];
  const float* b1     = (const float*)d_in[4];
  const float* w2     = (const float*)d_in[5];
  const float* b2     = (const float*)d_in[6];
  float*       out    = (float*)d_out;

  // Workspace (f16 units), ~54 MB total
  f16* ws = (f16*)d_ws;
  f16* obsT16  = ws + 0;          //  4,194,304
  f16* w1T     = ws + 4194304;    //    524,288
  f16* w2T     = ws + 4718592;    //  9,437,184
  f16* exp16   = ws + 14155776;   //  4,194,304
  f16* expT16  = ws + 18350080;   //  4,194,304
  f16* yT16    = ws + 22544384;   //  4,194,304
  float* rowpart = (float*)(ws + 26738688);   // 65,536 f32
  float* colpart = (float*)(ws + 26869760);   // 65,536 f32
  int*   order   = (int*)(ws + 27000832);     // 64 ints

  k_preplog<<<dim3(1889),     256, 0, stream>>>(obs, phi, w1, w2, action,
                                                obsT16, w1T, w2T, order,
                                                exp16, expT16, rowpart, colpart);
  k_hy8    <<<dim3(512),      512, 0, stream>>>(expT16, obsT16, colpart,
                                                w1T, b1, w2T, b2,
                                                action, order, yT16);
  k_out_s  <<<dim3(4, 4, 64), 256, 0, stream>>>(exp16, yT16, rowpart, out);
}

// Round 22
// 89.430 us; speedup vs baseline: 1.0623x; 1.0623x over previous
//
#include <hip/hip_runtime.h>

// Problem constants
#define B_   64
#define M_   256
#define D_   256
#define A_   18
#define E_   4
#define S_   64
#define ES_  256          // E_*S_ == M_
#define H_   512
#define K2_  (A_*D_)      // 4608

typedef _Float16 f16;
typedef _Float16 f16x4 __attribute__((ext_vector_type(4)));
typedef _Float16 f16x8 __attribute__((ext_vector_type(8)));
typedef float    f32x4 __attribute__((ext_vector_type(4)));

static __device__ __forceinline__ f16x8 cat8(f16x4 a, f16x4 b) {
  return __builtin_shufflevector(a, b, 0, 1, 2, 3, 4, 5, 6, 7);
}
static __device__ __forceinline__ f16x8 pack8(float4 u0, float4 u1) {
  f16x8 a;
  a[0] = (f16)u0.x; a[1] = (f16)u0.y; a[2] = (f16)u0.z; a[3] = (f16)u0.w;
  a[4] = (f16)u1.x; a[5] = (f16)u1.y; a[6] = (f16)u1.z; a[7] = (f16)u1.w;
  return a;
}

// async global->LDS, 16B per lane; lds dest is wave-uniform base (+lane*16 HW)
typedef const __attribute__((address_space(1))) unsigned int guint;
typedef __attribute__((address_space(3))) unsigned int luint;
static __device__ __forceinline__ void gload16(const f16* g, f16* l) {
  __builtin_amdgcn_global_load_lds((guint*)g, (luint*)l, 16, 0, 0);
}
#define VMCNT(n)  asm volatile("s_waitcnt vmcnt(" #n ")" ::: "memory")
#define LGKMCNT0  asm volatile("s_waitcnt lgkmcnt(0)" ::: "memory")
#define SBAR()    __builtin_amdgcn_s_barrier()
#define SCHED0()  __builtin_amdgcn_sched_barrier(0)
#define MFMA16(a, b, c) __builtin_amdgcn_mfma_f32_16x16x32_f16(a, b, c, 0, 0, 0)

// ===========================================================================
// k_preplog: ONE launch = all conversions + logits/exp/partial-sums.
// (R20 version — 64x64 transpose tiles, 3456 transpose blocks; measured
// 41.4 us. R21's 256x64 restructure regressed and was reverted.)
// Block ranges:
//   [0,1024)      obs fp32 [b][M][D] -> obsT16 [b][D][M]
//   [1024,1152)   w1 -> w1T   (per-e 256x512 -> 512x256)
//   [1152,3456)   w2 -> w2T   (per-e 512x4608 -> 4608x512)
//   [3456]        action rank-sort -> order
//   [3457,4481)   logits: exp16/expT16/rowpart/colpart (stages phi^T itself)
// ===========================================================================
__global__ __launch_bounds__(256) void k_preplog(
    const float* __restrict__ obs, const float* __restrict__ phi,
    const float* __restrict__ w1, const float* __restrict__ w2,
    const int* __restrict__ action,
    f16* __restrict__ obsT16, f16* __restrict__ w1T, f16* __restrict__ w2T,
    int* __restrict__ order,
    f16* __restrict__ exp16, f16* __restrict__ expT16,
    float* __restrict__ rowpart, float* __restrict__ colpart)
{
  __shared__ f16 Bs[64][264];                       // 33.8 KB
  f16 (*T)[68] = reinterpret_cast<f16(*)[68]>(&Bs[0][0]);  // alias (8.7 KB)
  const int bx = blockIdx.x;
  const int t  = threadIdx.x;

  if (bx < 3456) {
    const int rr = t >> 4, cc = (t & 15) * 4;
    const float* src; f16* dst; int R, C, r0, c0;
    if (bx < 1024) {
      const int x = bx & 3, y = (bx >> 2) & 3, z = bx >> 4;
      src = obs + (long)z * (M_ * D_); dst = obsT16 + (long)z * (M_ * D_);
      R = M_; C = D_; r0 = y * 64; c0 = x * 64;
    } else if (bx < 1152) {
      const int idx = bx - 1024;
      const int x = idx & 7, y = (idx >> 3) & 3, z = idx >> 5;
      src = w1 + (long)z * (D_ * H_); dst = w1T + (long)z * (H_ * D_);
      R = D_; C = H_; r0 = y * 64; c0 = x * 64;
    } else {
      const int idx = bx - 1152;
      const int x = idx % 72, rem = idx / 72, y = rem & 7, z = rem >> 3;
      src = w2 + (long)z * ((long)H_ * K2_); dst = w2T + (long)z * ((long)K2_ * H_);
      R = H_; C = K2_; r0 = y * 64; c0 = x * 64;
    }
#pragma unroll
    for (int p = 0; p < 4; ++p) {
      const int row = rr + p * 16;
      const float4 v = *reinterpret_cast<const float4*>(
          &src[(long)(r0 + row) * C + c0 + cc]);
      f16x4 h4; h4[0] = (f16)v.x; h4[1] = (f16)v.y;
      h4[2] = (f16)v.z; h4[3] = (f16)v.w;
      *reinterpret_cast<f16x4*>(&T[row][cc]) = h4;
    }
    __syncthreads();
#pragma unroll
    for (int p = 0; p < 4; ++p) {
      const int oc = rr + p * 16;
      f16x4 g;
#pragma unroll
      for (int i = 0; i < 4; ++i) g[i] = T[cc + i][oc];
      *reinterpret_cast<f16x4*>(&dst[(long)(c0 + oc) * R + r0 + cc]) = g;
    }
    return;
  }

  if (bx == 3456) {
    if (t < B_) {
      const int a = action[t];
      int rank = 0;
#pragma unroll 8
      for (int i = 0; i < B_; ++i) {
        const int ai = action[i];
        rank += (ai < a) || (ai == a && i < t);
      }
      order[rank] = t;
    }
    return;
  }

  const int lb  = bx - 3457;
  const int es0 = (lb & 3) * 64, m0g = ((lb >> 2) & 3) * 64;
  const int bz  = lb >> 4;
  const long bo = (long)bz * (M_ * D_);
  const long bb = (long)bz * (M_ * ES_);

  {
    const int el = t & 63, wg = t >> 6;
#pragma unroll
    for (int dp = 0; dp < D_; dp += 32) {
      f16x8 hv;
#pragma unroll
      for (int j = 0; j < 8; ++j)
        hv[j] = (f16)phi[(long)(dp + wg * 8 + j) * ES_ + es0 + el];
      *reinterpret_cast<f16x8*>(&Bs[el][dp + wg * 8]) = hv;
    }
  }
  __syncthreads();

  const int w = t >> 6, lane = t & 63;
  const int wr = w >> 1, wc = w & 1;
  const int lr = lane & 15, lk = (lane >> 4) * 8;
  const int orow = (lane >> 4) * 4;

  f32x4 acc[2][2] = {};
  const float* Ap = obs + bo + (long)(m0g + wr * 32 + lr) * D_ + lk;
#pragma unroll
  for (int k0 = 0; k0 < D_; k0 += 32) {
    const float4 u00 = *reinterpret_cast<const float4*>(Ap + k0);
    const float4 u01 = *reinterpret_cast<const float4*>(Ap + k0 + 4);
    const float4 u10 = *reinterpret_cast<const float4*>(Ap + 16 * D_ + k0);
    const float4 u11 = *reinterpret_cast<const float4*>(Ap + 16 * D_ + k0 + 4);
    const f16x8 a0 = pack8(u00, u01);
    const f16x8 a1 = pack8(u10, u11);
    const f16x8 b0 = *reinterpret_cast<const f16x8*>(&Bs[wc * 32 + lr][k0 + lk]);
    const f16x8 b1 = *reinterpret_cast<const f16x8*>(&Bs[wc * 32 + 16 + lr][k0 + lk]);
    acc[0][0] = MFMA16(a0, b0, acc[0][0]);
    acc[0][1] = MFMA16(a0, b1, acc[0][1]);
    acc[1][0] = MFMA16(a1, b0, acc[1][0]);
    acc[1][1] = MFMA16(a1, b1, acc[1][1]);
  }
  __syncthreads();   // Bs dead; reuse as T

#pragma unroll
  for (int fi = 0; fi < 2; ++fi)
#pragma unroll
    for (int fj = 0; fj < 2; ++fj) {
      const int gm = wr * 32 + fi * 16 + orow;
      const int gn = wc * 32 + fj * 16 + lr;
#pragma unroll
      for (int r = 0; r < 4; ++r)
        T[gm + r][gn] = (f16)__expf(acc[fi][fj][r]);
    }
  __syncthreads();

  {
    const int row = t >> 2, q = t & 3;
    f16x4 p0 = *reinterpret_cast<const f16x4*>(&T[row][q * 16 + 0]);
    f16x4 p1 = *reinterpret_cast<const f16x4*>(&T[row][q * 16 + 4]);
    f16x4 p2 = *reinterpret_cast<const f16x4*>(&T[row][q * 16 + 8]);
    f16x4 p3 = *reinterpret_cast<const f16x4*>(&T[row][q * 16 + 12]);
    f16* dst = exp16 + bb + (long)(m0g + row) * ES_ + es0 + q * 16;
    *reinterpret_cast<f16x8*>(dst)     = cat8(p0, p1);
    *reinterpret_cast<f16x8*>(dst + 8) = cat8(p2, p3);
  }
  {
    const int er = t >> 2, q = t & 3;
    f16x4 g[4];
#pragma unroll
    for (int j = 0; j < 4; ++j)
#pragma unroll
      for (int i = 0; i < 4; ++i)
        g[j][i] = T[q * 16 + j * 4 + i][er];
    f16* dst = expT16 + bb + (long)(es0 + er) * M_ + m0g + q * 16;
    *reinterpret_cast<f16x8*>(dst)     = cat8(g[0], g[1]);
    *reinterpret_cast<f16x8*>(dst + 8) = cat8(g[2], g[3]);
  }
  if (t < 64) {
    float s = 0.f;
#pragma unroll
    for (int i = 0; i < 16; ++i) {
      const f16x4 v = *reinterpret_cast<const f16x4*>(&T[t][i * 4]);
      s += (float)v[0] + (float)v[1] + (float)v[2] + (float)v[3];
    }
    rowpart[((long)bz * 256 + m0g + t) * 4 + (lb & 3)] = s;
  } else if (t < 128) {
    const int es = t - 64;
    float s = 0.f;
#pragma unroll
    for (int i = 0; i < 64; ++i) s += (float)T[i][es];
    colpart[((long)bz * 256 + es0 + es) * 4 + ((lb >> 2) & 3)] = s;
  }
}

// ===========================================================================
// k_hy8: fused slots->h->y, pipelined staging via raw s_barrier + counted
// vmcnt (unchanged from R20, 89.7 µs baseline).
// ===========================================================================
__global__ __launch_bounds__(512, 4) void k_hy8(
    const f16* __restrict__ expT16, const f16* __restrict__ obsT16,
    const float* __restrict__ colpart,
    const f16* __restrict__ w1T, const float* __restrict__ b1,
    const f16* __restrict__ w2T, const float* __restrict__ b2,
    const int* __restrict__ action, const int* __restrict__ order,
    f16* __restrict__ yT16)
{
  __shared__ f16 lds[40960];        // 80 KB exactly
  f16* stg = lds;                   // 2 x 8192
  f16* ssO = lds + 16384;           // 8192
  f16* hsO = lds + 24576;           // 16384

  const int bx = blockIdx.x;
  const int L  = (bx & 7) * 64 + (bx >> 3);   // XCD-chunk swizzle (bijective)
  const int sb = L >> 3, e = (L >> 1) & 3, half = L & 1;   // b-major decode
  const int b = order[sb];
  const int s0 = half * 32;
  int a = action[b];
  a = (a < 0) ? 0 : (a >= A_ ? A_ - 1 : a);

  const int t = threadIdx.x, w = t >> 6, lane = t & 63;
  const int lr = lane & 15, lk = (lane >> 4) * 8;
  const int seg = lane >> 4;
  const int orow = (lane >> 4) * 4;
  const int xorA = (lr & 7) << 3;

  const f16* srcB0 = obsT16 + (long)b * (D_ * M_);
  const f16* srcB1 = w1T + (long)e * (H_ * D_);
  const f16* srcB2 = w2T + (long)e * ((long)K2_ * H_) + (long)a * D_ * H_;
  const f16* ApG0  = expT16 + (long)b * (ES_ * M_)
                   + (long)(e * S_ + s0 + lr) * M_ + lk;

  // ======== GEMM0 (serial staging): ss = (1/colsum)*expT@obsT^T ============
  f32x4 acc00 = {}, acc01 = {}, acc10 = {}, acc11 = {};
#pragma unroll 1
  for (int kt = 0; kt < 8; ++kt) {
    __syncthreads();
#pragma unroll
    for (int p = 0; p < 2; ++p) {
      const int j = (w * 2 + p) * 64 + lane;
      const int row = j >> 2, sg = (j & 3) ^ (row & 3);
      gload16(srcB0 + (long)row * M_ + kt * 32 + sg * 8, stg + (w * 2 + p) * 512);
    }
    __syncthreads();
    const f16x8 a0 = *reinterpret_cast<const f16x8*>(ApG0 + kt * 32);
    const f16x8 a1 = *reinterpret_cast<const f16x8*>(ApG0 + 16 * M_ + kt * 32);
    const int r0 = w * 32 + lr, r1 = w * 32 + 16 + lr;
    const f16x8 b0 = *reinterpret_cast<const f16x8*>(&stg[r0 * 32 + ((seg ^ (r0 & 3)) * 8)]);
    const f16x8 b1 = *reinterpret_cast<const f16x8*>(&stg[r1 * 32 + ((seg ^ (r1 & 3)) * 8)]);
    acc00 = MFMA16(a0, b0, acc00); acc01 = MFMA16(a0, b1, acc01);
    acc10 = MFMA16(a1, b0, acc10); acc11 = MFMA16(a1, b1, acc11);
  }
  __syncthreads();

  // G1 prologue stage 0 (into stg)
#pragma unroll
  for (int p = 0; p < 4; ++p) {
    const int j = (w * 4 + p) * 64 + lane;
    const int row = j >> 2, sg = (j & 3) ^ (row & 3);
    gload16(srcB1 + (long)row * D_ + 0 * 32 + sg * 8, stg + (w * 4 + p) * 512);
  }
  // G0 epilogue -> ssO (XOR-swizzled)
  {
    f32x4 accs[2][2] = {{acc00, acc01}, {acc10, acc11}};
    const int n0 = w * 32;
#pragma unroll
    for (int fi = 0; fi < 2; ++fi) {
      float inv[4];
#pragma unroll
      for (int r = 0; r < 4; ++r) {
        const int ges = e * S_ + s0 + fi * 16 + orow + r;
        const float4 cp = *reinterpret_cast<const float4*>(
            &colpart[((long)b * 256 + ges) * 4]);
        inv[r] = 1.0f / (cp.x + cp.y + cp.z + cp.w);
      }
#pragma unroll
      for (int fj = 0; fj < 2; ++fj) {
        const int gn = n0 + fj * 16 + lr;
#pragma unroll
        for (int r = 0; r < 4; ++r) {
          const int row = fi * 16 + orow + r;
          ssO[row * 256 + (gn ^ ((row & 7) << 3))] = (f16)(accs[fi][fj][r] * inv[r]);
        }
      }
    }
  }
  // G1 prologue stage 1 (into hsO region)
#pragma unroll
  for (int p = 0; p < 4; ++p) {
    const int j = (w * 4 + p) * 64 + lane;
    const int row = j >> 2, sg = (j & 3) ^ (row & 3);
    gload16(srcB1 + (long)row * D_ + 1 * 32 + sg * 8, hsO + (w * 4 + p) * 512);
  }
  LGKMCNT0; SBAR(); SCHED0();

  // ======== GEMM1 (pipelined): hs = relu(ss @ w1T^T + b1) ==================
  f32x4 g1acc[2][4] = {};
#pragma unroll 1
  for (int kt = 0; kt < 7; ++kt) {
    VMCNT(4); SBAR(); SCHED0();
    f16* buf = (kt & 1) ? hsO : stg;
    {
      const f16x8 af0 = *reinterpret_cast<const f16x8*>(
          &ssO[lr * 256 + ((kt * 32 + lk) ^ xorA)]);
      const f16x8 af1 = *reinterpret_cast<const f16x8*>(
          &ssO[(16 + lr) * 256 + ((kt * 32 + lk) ^ xorA)]);
#pragma unroll
      for (int fj = 0; fj < 4; ++fj) {
        const int rB = w * 64 + fj * 16 + lr;
        const f16x8 bf = *reinterpret_cast<const f16x8*>(
            &buf[rB * 32 + ((seg ^ (rB & 3)) * 8)]);
        g1acc[0][fj] = MFMA16(af0, bf, g1acc[0][fj]);
        g1acc[1][fj] = MFMA16(af1, bf, g1acc[1][fj]);
      }
    }
    SBAR();
    if (kt < 6) {
#pragma unroll
      for (int p = 0; p < 4; ++p) {
        const int j = (w * 4 + p) * 64 + lane;
        const int row = j >> 2, sg = (j & 3) ^ (row & 3);
        gload16(srcB1 + (long)row * D_ + (kt + 2) * 32 + sg * 8, buf + (w * 4 + p) * 512);
      }
    }
  }
  VMCNT(0); SBAR(); SCHED0();
  {
    const f16x8 af0 = *reinterpret_cast<const f16x8*>(
        &ssO[lr * 256 + ((7 * 32 + lk) ^ xorA)]);
    const f16x8 af1 = *reinterpret_cast<const f16x8*>(
        &ssO[(16 + lr) * 256 + ((7 * 32 + lk) ^ xorA)]);
#pragma unroll
    for (int fj = 0; fj < 4; ++fj) {
      const int rB = w * 64 + fj * 16 + lr;
      const f16x8 bf = *reinterpret_cast<const f16x8*>(
          &hsO[rB * 32 + ((seg ^ (rB & 3)) * 8)]);
      g1acc[0][fj] = MFMA16(af0, bf, g1acc[0][fj]);
      g1acc[1][fj] = MFMA16(af1, bf, g1acc[1][fj]);
    }
  }
  SBAR();

  // G2 prologue stages 0,1 (into stg halves)
#pragma unroll
  for (int p = 0; p < 2; ++p) {
    const int j = (w * 2 + p) * 64 + lane;
    const int row = j >> 2, sg = (j & 3) ^ (row & 3);
    gload16(srcB2 + (long)row * H_ + 0 * 32 + sg * 8, stg + (w * 2 + p) * 512);
  }
#pragma unroll
  for (int p = 0; p < 2; ++p) {
    const int j = (w * 2 + p) * 64 + lane;
    const int row = j >> 2, sg = (j & 3) ^ (row & 3);
    gload16(srcB2 + (long)row * H_ + 1 * 32 + sg * 8, stg + 8192 + (w * 2 + p) * 512);
  }
  // G1 epilogue -> hsO (XOR-swizzled)
  {
    const int n1 = w * 64;
#pragma unroll
    for (int fi = 0; fi < 2; ++fi)
#pragma unroll
      for (int fj = 0; fj < 4; ++fj) {
        const int gn = n1 + fj * 16 + lr;
        const float bv = b1[e * H_ + gn];
#pragma unroll
        for (int r = 0; r < 4; ++r) {
          const int row = fi * 16 + orow + r;
          hsO[row * 512 + (gn ^ ((row & 7) << 3))] =
              (f16)fmaxf(g1acc[fi][fj][r] + bv, 0.f);
        }
      }
  }
  LGKMCNT0; SBAR(); SCHED0();

  // ======== GEMM2 (pipelined): y = hs @ w2T[a-slice]^T + b2 ================
  f32x4 acc2[2][2] = {};
#pragma unroll 1
  for (int kt = 0; kt < 15; ++kt) {
    VMCNT(2); SBAR(); SCHED0();
    f16* buf = stg + (kt & 1) * 8192;
    {
      const f16x8 af0 = *reinterpret_cast<const f16x8*>(
          &hsO[lr * 512 + ((kt * 32 + lk) ^ xorA)]);
      const f16x8 af1 = *reinterpret_cast<const f16x8*>(
          &hsO[(16 + lr) * 512 + ((kt * 32 + lk) ^ xorA)]);
#pragma unroll
      for (int fj = 0; fj < 2; ++fj) {
        const int rB = w * 32 + fj * 16 + lr;
        const f16x8 bf = *reinterpret_cast<const f16x8*>(
            &buf[rB * 32 + ((seg ^ (rB & 3)) * 8)]);
        acc2[0][fj] = MFMA16(af0, bf, acc2[0][fj]);
        acc2[1][fj] = MFMA16(af1, bf, acc2[1][fj]);
      }
    }
    SBAR();
    if (kt < 14) {
#pragma unroll
      for (int p = 0; p < 2; ++p) {
        const int j = (w * 2 + p) * 64 + lane;
        const int row = j >> 2, sg = (j & 3) ^ (row & 3);
        gload16(srcB2 + (long)row * H_ + (kt + 2) * 32 + sg * 8, buf + (w * 2 + p) * 512);
      }
    }
  }
  VMCNT(0); SBAR(); SCHED0();
  {
    const f16x8 af0 = *reinterpret_cast<const f16x8*>(
        &hsO[lr * 512 + ((15 * 32 + lk) ^ xorA)]);
    const f16x8 af1 = *reinterpret_cast<const f16x8*>(
        &hsO[(16 + lr) * 512 + ((15 * 32 + lk) ^ xorA)]);
#pragma unroll
    for (int fj = 0; fj < 2; ++fj) {
      const int rB = w * 32 + fj * 16 + lr;
      const f16x8 bf = *reinterpret_cast<const f16x8*>(
          &stg[8192 + rB * 32 + ((seg ^ (rB & 3)) * 8)]);
      acc2[0][fj] = MFMA16(af0, bf, acc2[0][fj]);
      acc2[1][fj] = MFMA16(af1, bf, acc2[1][fj]);
    }
  }
  // yT16 epilogue
  {
    const int n0_2 = w * 32;
#pragma unroll
    for (int fi = 0; fi < 2; ++fi)
#pragma unroll
      for (int fj = 0; fj < 2; ++fj) {
        const int gm = fi * 16 + orow;
        const int gn = n0_2 + fj * 16 + lr;
        const float bv = b2[e * K2_ + a * D_ + gn];
        f16x4 h4;
#pragma unroll
        for (int r = 0; r < 4; ++r) h4[r] = (f16)(acc2[fi][fj][r] + bv);
        *reinterpret_cast<f16x4*>(
            &yT16[(long)b * (D_ * ES_) + (long)gn * ES_ + e * S_ + s0 + gm]) = h4;
      }
  }
}

// ===========================================================================
// k_out_s: out[b][m][d] (fp32) = (1/rowsum[m]) * exp16[b] @ yT16[b]^T
// ===========================================================================
__global__ __launch_bounds__(256) void k_out_s(
    const f16* __restrict__ exp16, const f16* __restrict__ yT16,
    const float* __restrict__ rowpart, float* __restrict__ out)
{
  const int t = threadIdx.x;
  const int w = t >> 6, lane = t & 63;
  const int wr = w >> 1, wc = w & 1;
  const int m0 = blockIdx.y * 64 + wr * 32;
  const int n0 = blockIdx.x * 64 + wc * 32;
  const int lr = lane & 15, lk = (lane >> 4) * 8;
  const long b = blockIdx.z;

  f32x4 acc[2][2] = {};
  const f16* Ap = exp16 + b * (M_ * ES_) + (long)(m0 + lr) * ES_ + lk;
  const f16* Bp = yT16 + b * (D_ * ES_) + (long)(n0 + lr) * ES_ + lk;
#pragma unroll
  for (int k0 = 0; k0 < ES_; k0 += 32) {
    const f16x8 a0 = *reinterpret_cast<const f16x8*>(Ap + k0);
    const f16x8 a1 = *reinterpret_cast<const f16x8*>(Ap + 16 * ES_ + k0);
    const f16x8 b0 = *reinterpret_cast<const f16x8*>(Bp + k0);
    const f16x8 b1 = *reinterpret_cast<const f16x8*>(Bp + 16 * ES_ + k0);
    acc[0][0] = MFMA16(a0, b0, acc[0][0]);
    acc[0][1] = MFMA16(a0, b1, acc[0][1]);
    acc[1][0] = MFMA16(a1, b0, acc[1][0]);
    acc[1][1] = MFMA16(a1, b1, acc[1][1]);
  }

  const int orow = (lane >> 4) * 4;
  float* C = out + b * (M_ * D_);
#pragma unroll
  for (int fi = 0; fi < 2; ++fi) {
    float inv[4];
#pragma unroll
    for (int r = 0; r < 4; ++r) {
      const int gm = m0 + fi * 16 + orow + r;
      const float4 rp = *reinterpret_cast<const float4*>(&rowpart[((long)b * 256 + gm) * 4]);
      inv[r] = 1.0f / (rp.x + rp.y + rp.z + rp.w);
    }
#pragma unroll
    for (int fj = 0; fj < 2; ++fj) {
      const int gm = m0 + fi * 16 + orow;
      const int gn = n0 + fj * 16 + lr;
#pragma unroll
      for (int r = 0; r < 4; ++r)
        C[(long)(gm + r) * D_ + gn] = acc[fi][fj][r] * inv[r];
    }
  }
}

// ===========================================================================
extern "C" void kernel_launch(void* const* d_in, const int* in_sizes, int n_in,
                              void* d_out, int out_size, void* d_ws, size_t ws_size,
                              hipStream_t stream)
{
  const float* obs    = (const float*)d_in[0];
  const int*   action = (const int*)d_in[1];
  const float* phi    = (const float*)d_in[2];
  const float* w1     = (const float*)d_in[3];
  const float* b1     = (const float*)d_in[4];
  const float* w2     = (const float*)d_in[5];
  const float* b2     = (const float*)d_in[6];
  float*       out    = (float*)d_out;

  // Workspace (f16 units), ~54 MB total
  f16* ws = (f16*)d_ws;
  f16* obsT16  = ws + 0;          //  4,194,304
  f16* w1T     = ws + 4194304;    //    524,288
  f16* w2T     = ws + 4718592;    //  9,437,184
  f16* exp16   = ws + 14155776;   //  4,194,304
  f16* expT16  = ws + 18350080;   //  4,194,304
  f16* yT16    = ws + 22544384;   //  4,194,304
  float* rowpart = (float*)(ws + 26738688);   // 65,536 f32
  float* colpart = (float*)(ws + 26869760);   // 65,536 f32
  int*   order   = (int*)(ws + 27000832);     // 64 ints

  k_preplog<<<dim3(4481),     256, 0, stream>>>(obs, phi, w1, w2, action,
                                                obsT16, w1T, w2T, order,
                                                exp16, expT16, rowpart, colpart);
  k_hy8    <<<dim3(512),      512, 0, stream>>>(expT16, obsT16, colpart,
                                                w1T, b1, w2T, b2,
                                                action, order, yT16);
  k_out_s  <<<dim3(4, 4, 64), 256, 0, stream>>>(exp16, yT16, rowpart, out);
}

// Round 23
// 88.703 us; speedup vs baseline: 1.0710x; 1.0082x over previous
//
#include <hip/hip_runtime.h>

// Problem constants
#define B_   64
#define M_   256
#define D_   256
#define A_   18
#define E_   4
#define S_   64
#define ES_  256          // E_*S_ == M_
#define H_   512
#define K2_  (A_*D_)      // 4608

typedef _Float16 f16;
typedef _Float16 f16x4 __attribute__((ext_vector_type(4)));
typedef _Float16 f16x8 __attribute__((ext_vector_type(8)));
typedef float    f32x4 __attribute__((ext_vector_type(4)));

static __device__ __forceinline__ f16x8 cat8(f16x4 a, f16x4 b) {
  return __builtin_shufflevector(a, b, 0, 1, 2, 3, 4, 5, 6, 7);
}
static __device__ __forceinline__ f16x8 pack8(float4 u0, float4 u1) {
  f16x8 a;
  a[0] = (f16)u0.x; a[1] = (f16)u0.y; a[2] = (f16)u0.z; a[3] = (f16)u0.w;
  a[4] = (f16)u1.x; a[5] = (f16)u1.y; a[6] = (f16)u1.z; a[7] = (f16)u1.w;
  return a;
}

// async global->LDS, 16B per lane; lds dest is wave-uniform base (+lane*16 HW)
typedef const __attribute__((address_space(1))) unsigned int guint;
typedef __attribute__((address_space(3))) unsigned int luint;
static __device__ __forceinline__ void gload16(const f16* g, f16* l) {
  __builtin_amdgcn_global_load_lds((guint*)g, (luint*)l, 16, 0, 0);
}
#define VMCNT(n)  asm volatile("s_waitcnt vmcnt(" #n ")" ::: "memory")
#define LGKMCNT0  asm volatile("s_waitcnt lgkmcnt(0)" ::: "memory")
#define SBAR()    __builtin_amdgcn_s_barrier()
#define SCHED0()  __builtin_amdgcn_sched_barrier(0)
#define MFMA16(a, b, c) __builtin_amdgcn_mfma_f32_16x16x32_f16(a, b, c, 0, 0, 0)

// ===========================================================================
// k_preplog: ONE launch = all conversions + logits/exp/partial-sums.
// (R20/R22 version — 64x64 transpose tiles; measured 41.4-41.8 us.)
// ===========================================================================
__global__ __launch_bounds__(256) void k_preplog(
    const float* __restrict__ obs, const float* __restrict__ phi,
    const float* __restrict__ w1, const float* __restrict__ w2,
    const int* __restrict__ action,
    f16* __restrict__ obsT16, f16* __restrict__ w1T, f16* __restrict__ w2T,
    int* __restrict__ order,
    f16* __restrict__ exp16, f16* __restrict__ expT16,
    float* __restrict__ rowpart, float* __restrict__ colpart)
{
  __shared__ f16 Bs[64][264];                       // 33.8 KB
  f16 (*T)[68] = reinterpret_cast<f16(*)[68]>(&Bs[0][0]);  // alias (8.7 KB)
  const int bx = blockIdx.x;
  const int t  = threadIdx.x;

  if (bx < 3456) {
    const int rr = t >> 4, cc = (t & 15) * 4;
    const float* src; f16* dst; int R, C, r0, c0;
    if (bx < 1024) {
      const int x = bx & 3, y = (bx >> 2) & 3, z = bx >> 4;
      src = obs + (long)z * (M_ * D_); dst = obsT16 + (long)z * (M_ * D_);
      R = M_; C = D_; r0 = y * 64; c0 = x * 64;
    } else if (bx < 1152) {
      const int idx = bx - 1024;
      const int x = idx & 7, y = (idx >> 3) & 3, z = idx >> 5;
      src = w1 + (long)z * (D_ * H_); dst = w1T + (long)z * (H_ * D_);
      R = D_; C = H_; r0 = y * 64; c0 = x * 64;
    } else {
      const int idx = bx - 1152;
      const int x = idx % 72, rem = idx / 72, y = rem & 7, z = rem >> 3;
      src = w2 + (long)z * ((long)H_ * K2_); dst = w2T + (long)z * ((long)K2_ * H_);
      R = H_; C = K2_; r0 = y * 64; c0 = x * 64;
    }
#pragma unroll
    for (int p = 0; p < 4; ++p) {
      const int row = rr + p * 16;
      const float4 v = *reinterpret_cast<const float4*>(
          &src[(long)(r0 + row) * C + c0 + cc]);
      f16x4 h4; h4[0] = (f16)v.x; h4[1] = (f16)v.y;
      h4[2] = (f16)v.z; h4[3] = (f16)v.w;
      *reinterpret_cast<f16x4*>(&T[row][cc]) = h4;
    }
    __syncthreads();
#pragma unroll
    for (int p = 0; p < 4; ++p) {
      const int oc = rr + p * 16;
      f16x4 g;
#pragma unroll
      for (int i = 0; i < 4; ++i) g[i] = T[cc + i][oc];
      *reinterpret_cast<f16x4*>(&dst[(long)(c0 + oc) * R + r0 + cc]) = g;
    }
    return;
  }

  if (bx == 3456) {
    if (t < B_) {
      const int a = action[t];
      int rank = 0;
#pragma unroll 8
      for (int i = 0; i < B_; ++i) {
        const int ai = action[i];
        rank += (ai < a) || (ai == a && i < t);
      }
      order[rank] = t;
    }
    return;
  }

  const int lb  = bx - 3457;
  const int es0 = (lb & 3) * 64, m0g = ((lb >> 2) & 3) * 64;
  const int bz  = lb >> 4;
  const long bo = (long)bz * (M_ * D_);
  const long bb = (long)bz * (M_ * ES_);

  {
    const int el = t & 63, wg = t >> 6;
#pragma unroll
    for (int dp = 0; dp < D_; dp += 32) {
      f16x8 hv;
#pragma unroll
      for (int j = 0; j < 8; ++j)
        hv[j] = (f16)phi[(long)(dp + wg * 8 + j) * ES_ + es0 + el];
      *reinterpret_cast<f16x8*>(&Bs[el][dp + wg * 8]) = hv;
    }
  }
  __syncthreads();

  const int w = t >> 6, lane = t & 63;
  const int wr = w >> 1, wc = w & 1;
  const int lr = lane & 15, lk = (lane >> 4) * 8;
  const int orow = (lane >> 4) * 4;

  f32x4 acc[2][2] = {};
  const float* Ap = obs + bo + (long)(m0g + wr * 32 + lr) * D_ + lk;
#pragma unroll
  for (int k0 = 0; k0 < D_; k0 += 32) {
    const float4 u00 = *reinterpret_cast<const float4*>(Ap + k0);
    const float4 u01 = *reinterpret_cast<const float4*>(Ap + k0 + 4);
    const float4 u10 = *reinterpret_cast<const float4*>(Ap + 16 * D_ + k0);
    const float4 u11 = *reinterpret_cast<const float4*>(Ap + 16 * D_ + k0 + 4);
    const f16x8 a0 = pack8(u00, u01);
    const f16x8 a1 = pack8(u10, u11);
    const f16x8 b0 = *reinterpret_cast<const f16x8*>(&Bs[wc * 32 + lr][k0 + lk]);
    const f16x8 b1 = *reinterpret_cast<const f16x8*>(&Bs[wc * 32 + 16 + lr][k0 + lk]);
    acc[0][0] = MFMA16(a0, b0, acc[0][0]);
    acc[0][1] = MFMA16(a0, b1, acc[0][1]);
    acc[1][0] = MFMA16(a1, b0, acc[1][0]);
    acc[1][1] = MFMA16(a1, b1, acc[1][1]);
  }
  __syncthreads();   // Bs dead; reuse as T

#pragma unroll
  for (int fi = 0; fi < 2; ++fi)
#pragma unroll
    for (int fj = 0; fj < 2; ++fj) {
      const int gm = wr * 32 + fi * 16 + orow;
      const int gn = wc * 32 + fj * 16 + lr;
#pragma unroll
      for (int r = 0; r < 4; ++r)
        T[gm + r][gn] = (f16)__expf(acc[fi][fj][r]);
    }
  __syncthreads();

  {
    const int row = t >> 2, q = t & 3;
    f16x4 p0 = *reinterpret_cast<const f16x4*>(&T[row][q * 16 + 0]);
    f16x4 p1 = *reinterpret_cast<const f16x4*>(&T[row][q * 16 + 4]);
    f16x4 p2 = *reinterpret_cast<const f16x4*>(&T[row][q * 16 + 8]);
    f16x4 p3 = *reinterpret_cast<const f16x4*>(&T[row][q * 16 + 12]);
    f16* dst = exp16 + bb + (long)(m0g + row) * ES_ + es0 + q * 16;
    *reinterpret_cast<f16x8*>(dst)     = cat8(p0, p1);
    *reinterpret_cast<f16x8*>(dst + 8) = cat8(p2, p3);
  }
  {
    const int er = t >> 2, q = t & 3;
    f16x4 g[4];
#pragma unroll
    for (int j = 0; j < 4; ++j)
#pragma unroll
      for (int i = 0; i < 4; ++i)
        g[j][i] = T[q * 16 + j * 4 + i][er];
    f16* dst = expT16 + bb + (long)(es0 + er) * M_ + m0g + q * 16;
    *reinterpret_cast<f16x8*>(dst)     = cat8(g[0], g[1]);
    *reinterpret_cast<f16x8*>(dst + 8) = cat8(g[2], g[3]);
  }
  if (t < 64) {
    float s = 0.f;
#pragma unroll
    for (int i = 0; i < 16; ++i) {
      const f16x4 v = *reinterpret_cast<const f16x4*>(&T[t][i * 4]);
      s += (float)v[0] + (float)v[1] + (float)v[2] + (float)v[3];
    }
    rowpart[((long)bz * 256 + m0g + t) * 4 + (lb & 3)] = s;
  } else if (t < 128) {
    const int es = t - 64;
    float s = 0.f;
#pragma unroll
    for (int i = 0; i < 64; ++i) s += (float)T[i][es];
    colpart[((long)bz * 256 + es0 + es) * 4 + ((lb >> 2) & 3)] = s;
  }
}

// ===========================================================================
// k_hy9: R23 = R20's k_hy8 with (a) per-phase staging barriers REMOVED
// (all staging is wave-local: wave w stages exactly the LDS rows it reads —
// G0/G2 rows [w*32,(w+1)*32), G1 rows [w*64,(w+1)*64) — so per-wave vmcnt
// ordering suffices; block-shared ssO/hsO keep their lgkmcnt+barrier fences)
// and (b) GEMM2 pipeline deepened to 3 buffers (stg0, stg1, ssO-after-death).
// ===========================================================================
__global__ __launch_bounds__(512, 4) void k_hy9(
    const f16* __restrict__ expT16, const f16* __restrict__ obsT16,
    const float* __restrict__ colpart,
    const f16* __restrict__ w1T, const float* __restrict__ b1,
    const f16* __restrict__ w2T, const float* __restrict__ b2,
    const int* __restrict__ action, const int* __restrict__ order,
    f16* __restrict__ yT16)
{
  __shared__ f16 lds[40960];        // 80 KB exactly
  f16* stg = lds;                   // 2 x 8192 f16 (2 x 16 KB)
  f16* ssO = lds + 16384;           // 8192 f16 (16 KB)
  f16* hsO = lds + 24576;           // 16384 f16 (32 KB)

  const int bx = blockIdx.x;
  const int L  = (bx & 7) * 64 + (bx >> 3);   // XCD-chunk swizzle (bijective)
  const int sb = L >> 3, e = (L >> 1) & 3, half = L & 1;   // b-major decode
  const int b = order[sb];
  const int s0 = half * 32;
  int a = action[b];
  a = (a < 0) ? 0 : (a >= A_ ? A_ - 1 : a);

  const int t = threadIdx.x, w = t >> 6, lane = t & 63;
  const int lr = lane & 15, lk = (lane >> 4) * 8;
  const int seg = lane >> 4;
  const int orow = (lane >> 4) * 4;
  const int xorA = (lr & 7) << 3;

  const f16* srcB0 = obsT16 + (long)b * (D_ * M_);
  const f16* srcB1 = w1T + (long)e * (H_ * D_);
  const f16* srcB2 = w2T + (long)e * ((long)K2_ * H_) + (long)a * D_ * H_;
  const f16* ApG0  = expT16 + (long)b * (ES_ * M_)
                   + (long)(e * S_ + s0 + lr) * M_ + lk;

  // ======== GEMM0 (serial staging, mixed global A-loads -> full drains) ====
  f32x4 acc00 = {}, acc01 = {}, acc10 = {}, acc11 = {};
#pragma unroll 1
  for (int kt = 0; kt < 8; ++kt) {
    __syncthreads();
#pragma unroll
    for (int p = 0; p < 2; ++p) {
      const int j = (w * 2 + p) * 64 + lane;
      const int row = j >> 2, sg = (j & 3) ^ (row & 3);
      gload16(srcB0 + (long)row * M_ + kt * 32 + sg * 8, stg + (w * 2 + p) * 512);
    }
    __syncthreads();
    const f16x8 a0 = *reinterpret_cast<const f16x8*>(ApG0 + kt * 32);
    const f16x8 a1 = *reinterpret_cast<const f16x8*>(ApG0 + 16 * M_ + kt * 32);
    const int r0 = w * 32 + lr, r1 = w * 32 + 16 + lr;
    const f16x8 b0 = *reinterpret_cast<const f16x8*>(&stg[r0 * 32 + ((seg ^ (r0 & 3)) * 8)]);
    const f16x8 b1 = *reinterpret_cast<const f16x8*>(&stg[r1 * 32 + ((seg ^ (r1 & 3)) * 8)]);
    acc00 = MFMA16(a0, b0, acc00); acc01 = MFMA16(a0, b1, acc01);
    acc10 = MFMA16(a1, b0, acc10); acc11 = MFMA16(a1, b1, acc11);
  }
  __syncthreads();

  // G1 prologue stage 0 (into stg as one 32KB buffer)
#pragma unroll
  for (int p = 0; p < 4; ++p) {
    const int j = (w * 4 + p) * 64 + lane;
    const int row = j >> 2, sg = (j & 3) ^ (row & 3);
    gload16(srcB1 + (long)row * D_ + 0 * 32 + sg * 8, stg + (w * 4 + p) * 512);
  }
  // G0 epilogue -> ssO (XOR-swizzled)
  {
    f32x4 accs[2][2] = {{acc00, acc01}, {acc10, acc11}};
    const int n0 = w * 32;
#pragma unroll
    for (int fi = 0; fi < 2; ++fi) {
      float inv[4];
#pragma unroll
      for (int r = 0; r < 4; ++r) {
        const int ges = e * S_ + s0 + fi * 16 + orow + r;
        const float4 cp = *reinterpret_cast<const float4*>(
            &colpart[((long)b * 256 + ges) * 4]);
        inv[r] = 1.0f / (cp.x + cp.y + cp.z + cp.w);
      }
#pragma unroll
      for (int fj = 0; fj < 2; ++fj) {
        const int gn = n0 + fj * 16 + lr;
#pragma unroll
        for (int r = 0; r < 4; ++r) {
          const int row = fi * 16 + orow + r;
          ssO[row * 256 + (gn ^ ((row & 7) << 3))] = (f16)(accs[fi][fj][r] * inv[r]);
        }
      }
    }
  }
  // G1 prologue stage 1 (into hsO region)
#pragma unroll
  for (int p = 0; p < 4; ++p) {
    const int j = (w * 4 + p) * 64 + lane;
    const int row = j >> 2, sg = (j & 3) ^ (row & 3);
    gload16(srcB1 + (long)row * D_ + 1 * 32 + sg * 8, hsO + (w * 4 + p) * 512);
  }
  LGKMCNT0; SBAR(); SCHED0();       // ssO (block-shared A) visible

  // ======== GEMM1 (pipelined, barrier-free staging): hs = relu(ss@w1T^T) ===
  f32x4 g1acc[2][4] = {};
#pragma unroll 1
  for (int kt = 0; kt < 7; ++kt) {
    VMCNT(4); SCHED0();             // own stage kt landed (wave-local rows)
    f16* buf = (kt & 1) ? hsO : stg;
    {
      const f16x8 af0 = *reinterpret_cast<const f16x8*>(
          &ssO[lr * 256 + ((kt * 32 + lk) ^ xorA)]);
      const f16x8 af1 = *reinterpret_cast<const f16x8*>(
          &ssO[(16 + lr) * 256 + ((kt * 32 + lk) ^ xorA)]);
#pragma unroll
      for (int fj = 0; fj < 4; ++fj) {
        const int rB = w * 64 + fj * 16 + lr;
        const f16x8 bf = *reinterpret_cast<const f16x8*>(
            &buf[rB * 32 + ((seg ^ (rB & 3)) * 8)]);
        g1acc[0][fj] = MFMA16(af0, bf, g1acc[0][fj]);
        g1acc[1][fj] = MFMA16(af1, bf, g1acc[1][fj]);
      }
    }
    if (kt < 6) {
#pragma unroll
      for (int p = 0; p < 4; ++p) {
        const int j = (w * 4 + p) * 64 + lane;
        const int row = j >> 2, sg = (j & 3) ^ (row & 3);
        gload16(srcB1 + (long)row * D_ + (kt + 2) * 32 + sg * 8, buf + (w * 4 + p) * 512);
      }
    }
  }
  VMCNT(0); SCHED0();               // peel kt=7 (buf = hsO)
  {
    const f16x8 af0 = *reinterpret_cast<const f16x8*>(
        &ssO[lr * 256 + ((7 * 32 + lk) ^ xorA)]);
    const f16x8 af1 = *reinterpret_cast<const f16x8*>(
        &ssO[(16 + lr) * 256 + ((7 * 32 + lk) ^ xorA)]);
#pragma unroll
    for (int fj = 0; fj < 4; ++fj) {
      const int rB = w * 64 + fj * 16 + lr;
      const f16x8 bf = *reinterpret_cast<const f16x8*>(
          &hsO[rB * 32 + ((seg ^ (rB & 3)) * 8)]);
      g1acc[0][fj] = MFMA16(af0, bf, g1acc[0][fj]);
      g1acc[1][fj] = MFMA16(af1, bf, g1acc[1][fj]);
    }
  }
  SBAR();   // all waves done reading ssO (A) + hsO staging before reuse

  // G2 prologue stages 0,1,2 (bufs: stg0, stg1, ssO — ssO now dead)
#pragma unroll
  for (int p = 0; p < 2; ++p) {
    const int j = (w * 2 + p) * 64 + lane;
    const int row = j >> 2, sg = (j & 3) ^ (row & 3);
    gload16(srcB2 + (long)row * H_ + 0 * 32 + sg * 8, stg + (w * 2 + p) * 512);
  }
#pragma unroll
  for (int p = 0; p < 2; ++p) {
    const int j = (w * 2 + p) * 64 + lane;
    const int row = j >> 2, sg = (j & 3) ^ (row & 3);
    gload16(srcB2 + (long)row * H_ + 1 * 32 + sg * 8, stg + 8192 + (w * 2 + p) * 512);
  }
#pragma unroll
  for (int p = 0; p < 2; ++p) {
    const int j = (w * 2 + p) * 64 + lane;
    const int row = j >> 2, sg = (j & 3) ^ (row & 3);
    gload16(srcB2 + (long)row * H_ + 2 * 32 + sg * 8, ssO + (w * 2 + p) * 512);
  }
  // G1 epilogue -> hsO (XOR-swizzled)
  {
    const int n1 = w * 64;
#pragma unroll
    for (int fi = 0; fi < 2; ++fi)
#pragma unroll
      for (int fj = 0; fj < 4; ++fj) {
        const int gn = n1 + fj * 16 + lr;
        const float bv = b1[e * H_ + gn];
#pragma unroll
        for (int r = 0; r < 4; ++r) {
          const int row = fi * 16 + orow + r;
          hsO[row * 512 + (gn ^ ((row & 7) << 3))] =
              (f16)fmaxf(g1acc[fi][fj][r] + bv, 0.f);
        }
      }
  }
  LGKMCNT0; SBAR(); SCHED0();       // hsO (block-shared A) visible

  // ======== GEMM2 (3-deep pipelined, barrier-free staging) =================
  f32x4 acc2[2][2] = {};
#pragma unroll 1
  for (int kt = 0; kt < 13; ++kt) {
    VMCNT(4); SCHED0();             // own stage kt landed; kt+1,kt+2 in flight
    const int rsel = kt % 3;
    f16* buf = (rsel == 0) ? stg : (rsel == 1) ? (stg + 8192) : ssO;
    {
      const f16x8 af0 = *reinterpret_cast<const f16x8*>(
          &hsO[lr * 512 + ((kt * 32 + lk) ^ xorA)]);
      const f16x8 af1 = *reinterpret_cast<const f16x8*>(
          &hsO[(16 + lr) * 512 + ((kt * 32 + lk) ^ xorA)]);
#pragma unroll
      for (int fj = 0; fj < 2; ++fj) {
        const int rB = w * 32 + fj * 16 + lr;
        const f16x8 bf = *reinterpret_cast<const f16x8*>(
            &buf[rB * 32 + ((seg ^ (rB & 3)) * 8)]);
        acc2[0][fj] = MFMA16(af0, bf, acc2[0][fj]);
        acc2[1][fj] = MFMA16(af1, bf, acc2[1][fj]);
      }
    }
    // issue stage kt+3 into the buffer just consumed (wave-local rows)
#pragma unroll
    for (int p = 0; p < 2; ++p) {
      const int j = (w * 2 + p) * 64 + lane;
      const int row = j >> 2, sg = (j & 3) ^ (row & 3);
      gload16(srcB2 + (long)row * H_ + (kt + 3) * 32 + sg * 8, buf + (w * 2 + p) * 512);
    }
  }
  // peels: stage s consumed from buf s%3
#pragma unroll 1
  for (int kt = 13; kt < 16; ++kt) {
    if (kt == 13) { VMCNT(4); } else if (kt == 14) { VMCNT(2); } else { VMCNT(0); }
    SCHED0();
    const int rsel = kt % 3;
    f16* buf = (rsel == 0) ? stg : (rsel == 1) ? (stg + 8192) : ssO;
    const f16x8 af0 = *reinterpret_cast<const f16x8*>(
        &hsO[lr * 512 + ((kt * 32 + lk) ^ xorA)]);
    const f16x8 af1 = *reinterpret_cast<const f16x8*>(
        &hsO[(16 + lr) * 512 + ((kt * 32 + lk) ^ xorA)]);
#pragma unroll
    for (int fj = 0; fj < 2; ++fj) {
      const int rB = w * 32 + fj * 16 + lr;
      const f16x8 bf = *reinterpret_cast<const f16x8*>(
          &buf[rB * 32 + ((seg ^ (rB & 3)) * 8)]);
      acc2[0][fj] = MFMA16(af0, bf, acc2[0][fj]);
      acc2[1][fj] = MFMA16(af1, bf, acc2[1][fj]);
    }
  }
  // yT16 epilogue: yT16[b][d][es = e*64 + s0 + s]
  {
    const int n0_2 = w * 32;
#pragma unroll
    for (int fi = 0; fi < 2; ++fi)
#pragma unroll
      for (int fj = 0; fj < 2; ++fj) {
        const int gm = fi * 16 + orow;
        const int gn = n0_2 + fj * 16 + lr;
        const float bv = b2[e * K2_ + a * D_ + gn];
        f16x4 h4;
#pragma unroll
        for (int r = 0; r < 4; ++r) h4[r] = (f16)(acc2[fi][fj][r] + bv);
        *reinterpret_cast<f16x4*>(
            &yT16[(long)b * (D_ * ES_) + (long)gn * ES_ + e * S_ + s0 + gm]) = h4;
      }
  }
}

// ===========================================================================
// k_out_s: out[b][m][d] (fp32) = (1/rowsum[m]) * exp16[b] @ yT16[b]^T
// ===========================================================================
__global__ __launch_bounds__(256) void k_out_s(
    const f16* __restrict__ exp16, const f16* __restrict__ yT16,
    const float* __restrict__ rowpart, float* __restrict__ out)
{
  const int t = threadIdx.x;
  const int w = t >> 6, lane = t & 63;
  const int wr = w >> 1, wc = w & 1;
  const int m0 = blockIdx.y * 64 + wr * 32;
  const int n0 = blockIdx.x * 64 + wc * 32;
  const int lr = lane & 15, lk = (lane >> 4) * 8;
  const long b = blockIdx.z;

  f32x4 acc[2][2] = {};
  const f16* Ap = exp16 + b * (M_ * ES_) + (long)(m0 + lr) * ES_ + lk;
  const f16* Bp = yT16 + b * (D_ * ES_) + (long)(n0 + lr) * ES_ + lk;
#pragma unroll
  for (int k0 = 0; k0 < ES_; k0 += 32) {
    const f16x8 a0 = *reinterpret_cast<const f16x8*>(Ap + k0);
    const f16x8 a1 = *reinterpret_cast<const f16x8*>(Ap + 16 * ES_ + k0);
    const f16x8 b0 = *reinterpret_cast<const f16x8*>(Bp + k0);
    const f16x8 b1 = *reinterpret_cast<const f16x8*>(Bp + 16 * ES_ + k0);
    acc[0][0] = MFMA16(a0, b0, acc[0][0]);
    acc[0][1] = MFMA16(a0, b1, acc[0][1]);
    acc[1][0] = MFMA16(a1, b0, acc[1][0]);
    acc[1][1] = MFMA16(a1, b1, acc[1][1]);
  }

  const int orow = (lane >> 4) * 4;
  float* C = out + b * (M_ * D_);
#pragma unroll
  for (int fi = 0; fi < 2; ++fi) {
    float inv[4];
#pragma unroll
    for (int r = 0; r < 4; ++r) {
      const int gm = m0 + fi * 16 + orow + r;
      const float4 rp = *reinterpret_cast<const float4*>(&rowpart[((long)b * 256 + gm) * 4]);
      inv[r] = 1.0f / (rp.x + rp.y + rp.z + rp.w);
    }
#pragma unroll
    for (int fj = 0; fj < 2; ++fj) {
      const int gm = m0 + fi * 16 + orow;
      const int gn = n0 + fj * 16 + lr;
#pragma unroll
      for (int r = 0; r < 4; ++r)
        C[(long)(gm + r) * D_ + gn] = acc[fi][fj][r] * inv[r];
    }
  }
}

// ===========================================================================
extern "C" void kernel_launch(void* const* d_in, const int* in_sizes, int n_in,
                              void* d_out, int out_size, void* d_ws, size_t ws_size,
                              hipStream_t stream)
{
  const float* obs    = (const float*)d_in[0];
  const int*   action = (const int*)d_in[1];
  const float* phi    = (const float*)d_in[2];
  const float* w1     = (const float*)d_in[3];
  const float* b1     = (const float*)d_in[4];
  const float* w2     = (const float*)d_in[5];
  const float* b2     = (const float*)d_in[6];
  float*       out    = (float*)d_out;

  // Workspace (f16 units), ~54 MB total
  f16* ws = (f16*)d_ws;
  f16* obsT16  = ws + 0;          //  4,194,304
  f16* w1T     = ws + 4194304;    //    524,288
  f16* w2T     = ws + 4718592;    //  9,437,184
  f16* exp16   = ws + 14155776;   //  4,194,304
  f16* expT16  = ws + 18350080;   //  4,194,304
  f16* yT16    = ws + 22544384;   //  4,194,304
  float* rowpart = (float*)(ws + 26738688);   // 65,536 f32
  float* colpart = (float*)(ws + 26869760);   // 65,536 f32
  int*   order   = (int*)(ws + 27000832);     // 64 ints

  k_preplog<<<dim3(4481),     256, 0, stream>>>(obs, phi, w1, w2, action,
                                                obsT16, w1T, w2T, order,
                                                exp16, expT16, rowpart, colpart);
  k_hy9    <<<dim3(512),      512, 0, stream>>>(expT16, obsT16, colpart,
                                                w1T, b1, w2T, b2,
                                                action, order, yT16);
  k_out_s  <<<dim3(4, 4, 64), 256, 0, stream>>>(exp16, yT16, rowpart, out);
}